// Round 6
// baseline (871.108 us; speedup 1.0000x reference)
//
#include <hip/hip_runtime.h>
#include <math.h>

#define NC    10
#define BATCH 256
#define IC    1152
#define LDIM  8
#define OC    16

#define NCH   64
#define CH    (IC/NCH)        // 18 i's per block
#define NBLK  (NC*NCH)        // 640 blocks = 2.5/CU (co-resident at 3/CU cap)
#define NTHR  256
#define NTOT  (NC*BATCH*OC)   // 40960
#define NRED  (NTOT/NTHR)     // 160 reduction blocks

__device__ __forceinline__ int xcd_swizzle(int bid, int nwg) {
    int cpx = nwg >> 3;
    return (bid & 7) * cpx + (bid >> 3);
}

// Monotonic grid barrier: counter zeroed per launch; barrier k waits for k*NBLK.
// RELEASE add publishes this block's stores; ACQUIRE spin-load pulls remote
// stores (agent scope -> cross-XCD L2 writeback/invalidate).
__device__ __forceinline__ void gbar(unsigned* c, unsigned target) {
    __syncthreads();   // all block stores drained before arrival
    if (threadIdx.x == 0) {
        __hip_atomic_fetch_add(c, 1u, __ATOMIC_RELEASE, __HIP_MEMORY_SCOPE_AGENT);
        while (__hip_atomic_load(c, __ATOMIC_ACQUIRE, __HIP_MEMORY_SCOPE_AGENT) < target)
            __builtin_amdgcn_s_sleep(2);
    }
    __syncthreads();
}

// ---------------------------------------------------------------------------
// One fused kernel. block = (n, ch of 18 i's), thread = b.
// Cross-block data: s_part -> s (+n2) only. betaT/invd are block-local.
// ---------------------------------------------------------------------------
__global__ __launch_bounds__(256, 3) void caps_fused(
    const float* __restrict__ x, const float* __restrict__ w,
    float* __restrict__ xT, float* __restrict__ betaT,
    float* __restrict__ invd, float* __restrict__ s,
    float* __restrict__ s_part, float* __restrict__ n2_part,
    unsigned* __restrict__ bar_cnt, float* __restrict__ out)
{
    int t  = threadIdx.x;                 // = b
    int lane = t & 63, wid = t >> 6;
    int wg = xcd_swizzle(blockIdx.x, NBLK);
    int n  = wg >> 6, ch = wg & 63;
    int i0 = ch * CH;
    unsigned bar = 1;

    __shared__ float redA[CH][4];   // k4 denom partials
    __shared__ float redW[4];       // generic 4-wave reduce
    __shared__ float sc_sh;

    // ---- phase 0: transpose x[b][i][l] -> xT[i][b][l] ----
    for (int u = blockIdx.x * NTHR + t; u < IC * BATCH * 2; u += NBLK * NTHR) {
        int i = u >> 9, r = u & 511, b = r >> 1, h = r & 1;
        reinterpret_cast<float4*>(xT)[u] =
            reinterpret_cast<const float4*>(x)[((size_t)b * IC + i) * 2 + h];
    }
    gbar(bar_cnt, (bar++) * NBLK);

    for (int iter = 0; iter < 3; ++iter) {
        // ---- phase 1 (k2): sp[o] = sum_{i in chunk} c * priors ----
        float sp[OC];
#pragma unroll
        for (int o = 0; o < OC; ++o) sp[o] = 0.f;

        for (int ii = 0; ii < CH; ++ii) {
            int i = i0 + ii;
            const float4* xp = reinterpret_cast<const float4*>(xT)
                             + ((size_t)i * BATCH + t) * 2;
            float4 xa = xp[0], xb = xp[1];
            float xr[8] = {xa.x, xa.y, xa.z, xa.w, xb.x, xb.y, xb.z, xb.w};

            const float* wp = w + (size_t)__builtin_amdgcn_readfirstlane(
                                      (n * IC + i) * (LDIM * OC));  // uniform -> s_load
            float p[OC];
#pragma unroll
            for (int o = 0; o < OC; ++o) p[o] = 0.f;
#pragma unroll
            for (int l = 0; l < LDIM; ++l)
#pragma unroll
                for (int o = 0; o < OC; ++o)
                    p[o] += wp[l * OC + o] * xr[l];

            float c;
            if (iter == 0) {
                c = 1.0f / 256.0f;                 // softmax of zeros over B=256
            } else {
                float be = betaT[((size_t)n * IC + i) * BATCH + t];  // coalesced
                c = __expf(be) * invd[n * IC + i];
            }
#pragma unroll
            for (int o = 0; o < OC; ++o) sp[o] += c * p[o];
        }
        {
            float4* dst = reinterpret_cast<float4*>(s_part)
                        + (((size_t)ch * NC + n) * BATCH + t) * 4;
            dst[0] = make_float4(sp[0],  sp[1],  sp[2],  sp[3]);
            dst[1] = make_float4(sp[4],  sp[5],  sp[6],  sp[7]);
            dst[2] = make_float4(sp[8],  sp[9],  sp[10], sp[11]);
            dst[3] = make_float4(sp[12], sp[13], sp[14], sp[15]);
        }
        gbar(bar_cnt, (bar++) * NBLK);

        // ---- phase 2: first 160 blocks reduce s_part -> s, n2 partials ----
        if (blockIdx.x < NRED) {
            int idx = blockIdx.x * NTHR + t;
            float acc = 0.f;
            for (int c2 = 0; c2 < NCH; ++c2) acc += s_part[(size_t)c2 * NTOT + idx];
            s[idx] = acc;
            float q = acc * acc;
#pragma unroll
            for (int m = 32; m >= 1; m >>= 1) q += __shfl_xor(q, m, 64);
            if (lane == 0) redW[wid] = q;
            __syncthreads();
            if (t == 0) n2_part[blockIdx.x] = redW[0] + redW[1] + redW[2] + redW[3];
        }
        gbar(bar_cnt, (bar++) * NBLK);

        // ---- phase 3: every block redundantly reduces n2_part -> scale ----
        {
            float q = (t < NRED) ? n2_part[t] : 0.f;
#pragma unroll
            for (int m = 32; m >= 1; m >>= 1) q += __shfl_xor(q, m, 64);
            if (lane == 0) redW[wid] = q;
            __syncthreads();
            if (t == 0) {
                float n2 = redW[0] + redW[1] + redW[2] + redW[3];
                sc_sh = sqrtf(n2) / (1.0f + n2);
            }
            __syncthreads();
        }
        float sc = sc_sh;

        if (iter < 2) {
            // ---- phase 4 (k4): beta update + fused softmax denom ----
            float v[OC];
            {
                const float4* svp = reinterpret_cast<const float4*>(s)
                                  + ((size_t)n * BATCH + t) * 4;
                float4 a = svp[0], b4 = svp[1], c4 = svp[2], d4 = svp[3];
                v[0]=a.x*sc;  v[1]=a.y*sc;  v[2]=a.z*sc;  v[3]=a.w*sc;
                v[4]=b4.x*sc; v[5]=b4.y*sc; v[6]=b4.z*sc; v[7]=b4.w*sc;
                v[8]=c4.x*sc; v[9]=c4.y*sc; v[10]=c4.z*sc;v[11]=c4.w*sc;
                v[12]=d4.x*sc;v[13]=d4.y*sc;v[14]=d4.z*sc;v[15]=d4.w*sc;
            }
            for (int ii = 0; ii < CH; ++ii) {
                int i = i0 + ii;
                const float4* xp = reinterpret_cast<const float4*>(xT)
                                 + ((size_t)i * BATCH + t) * 2;
                float4 xa = xp[0], xb = xp[1];
                float xr[8] = {xa.x, xa.y, xa.z, xa.w, xb.x, xb.y, xb.z, xb.w};

                const float* wp = w + (size_t)__builtin_amdgcn_readfirstlane(
                                          (n * IC + i) * (LDIM * OC));
                float p[OC];
#pragma unroll
                for (int o = 0; o < OC; ++o) p[o] = 0.f;
#pragma unroll
                for (int l = 0; l < LDIM; ++l)
#pragma unroll
                    for (int o = 0; o < OC; ++o)
                        p[o] += wp[l * OC + o] * xr[l];

                float dot = 0.f;
#pragma unroll
                for (int o = 0; o < OC; ++o) dot += p[o] * v[o];

                size_t bidx = ((size_t)n * IC + i) * BATCH + t;   // coalesced
                float bnew = (iter == 0) ? dot : (betaT[bidx] + dot);
                betaT[bidx] = bnew;

                float e = __expf(bnew);
#pragma unroll
                for (int m = 1; m < 64; m <<= 1) e += __shfl_xor(e, m, 64);
                if (lane == 0) redA[ii][wid] = e;
            }
            __syncthreads();
            if (t < CH)
                invd[n * IC + i0 + t] =
                    1.0f / (redA[t][0] + redA[t][1] + redA[t][2] + redA[t][3]);
            __syncthreads();   // invd/redA/betaT ready before next iter's phase 1
        } else {
            // ---- final: out = s * scale ----
            if (blockIdx.x < NRED) {
                int idx = blockIdx.x * NTHR + t;
                out[idx] = s[idx] * sc;
            }
        }
    }
}

// ---------------------------------------------------------------------------
extern "C" void kernel_launch(void* const* d_in, const int* in_sizes, int n_in,
                              void* d_out, int out_size, void* d_ws, size_t ws_size,
                              hipStream_t stream)
{
    const float* x = (const float*)d_in[0];   // [256,1152,8]
    const float* w = (const float*)d_in[1];   // [10,1152,8,16]
    float* out = (float*)d_out;               // 40960 floats
    float* ws  = (float*)d_ws;

    float* xT      = ws;                                        // 2,359,296
    float* betaT   = xT + (size_t)IC * BATCH * LDIM;            // 2,949,120
    float* invd    = betaT + (size_t)NC * IC * BATCH;           //    11,520
    float* s       = invd + (size_t)NC * IC;                    //    40,960
    float* s_part  = s + (size_t)NC * BATCH * OC;               // 2,621,440
    float* n2_part = s_part + (size_t)NCH * NC * BATCH * OC;    //       160
    unsigned* bar_cnt = (unsigned*)(n2_part + 160);             //         1
    // total ~32 MB of workspace

    (void)hipMemsetAsync(bar_cnt, 0, sizeof(unsigned), stream);  // barrier reset
    caps_fused<<<dim3(NBLK), dim3(NTHR), 0, stream>>>(
        x, w, xT, betaT, invd, s, s_part, n2_part, bar_cnt, out);
}

// Round 7
// 98.121 us; speedup vs baseline: 8.8779x; 8.8779x over previous
//
#include <hip/hip_runtime.h>
#include <math.h>

#define NC    10
#define BATCH 256
#define IC    1152
#define LDIM  8
#define OC    16

#define NCH   96
#define CH    (IC/NCH)        // 12 i's per block
#define NBLK  (NC*NCH)        // 960 blocks, %8==0 -> bijective XCD swizzle
#define NTHR  256
#define NTOT  (NC*BATCH*OC)   // 40960
#define NRED  (NTOT/NTHR)     // 160 reduction blocks

__device__ __forceinline__ int xcd_swizzle(int bid, int nwg) {
    int cpx = nwg >> 3;
    return (bid & 7) * cpx + (bid >> 3);
}

// ---------------------------------------------------------------------------
// K0: transpose x[b][i][l] -> xT[i][b][l] (coalesced thread=b loads later)
// ---------------------------------------------------------------------------
__global__ __launch_bounds__(256) void k0_xT(const float* __restrict__ x,
                                             float* __restrict__ xT)
{
    int u = blockIdx.x * 256 + threadIdx.x;       // < 589824
    int i = u >> 9, r = u & 511, b = r >> 1, h = r & 1;
    reinterpret_cast<float4*>(xT)[u] =
        reinterpret_cast<const float4*>(x)[((size_t)b * IC + i) * 2 + h];
}

// ---------------------------------------------------------------------------
// KA: iter-0 s partials. c uniform = 1/256 -> s0_part = (1/256) * sum_i p.
// thread = b; w lane-uniform (scalar loads); xT coalesced.
// ---------------------------------------------------------------------------
__global__ __launch_bounds__(256) void kA(
    const float* __restrict__ xT, const float* __restrict__ w,
    float* __restrict__ s_part)
{
    int wg = xcd_swizzle(blockIdx.x, NBLK);
    int n  = wg / NCH, ch = wg % NCH;
    int i0 = ch * CH;
    int t  = threadIdx.x;            // = b

    float sp[OC];
#pragma unroll
    for (int o = 0; o < OC; ++o) sp[o] = 0.f;

    for (int ii = 0; ii < CH; ++ii) {
        int i = i0 + ii;
        const float4* xp = reinterpret_cast<const float4*>(xT)
                         + ((size_t)i * BATCH + t) * 2;
        float4 xa = xp[0], xb = xp[1];
        float xr[8] = {xa.x, xa.y, xa.z, xa.w, xb.x, xb.y, xb.z, xb.w};
        const float* wp = w + (size_t)__builtin_amdgcn_readfirstlane(
                                  (n * IC + i) * (LDIM * OC));
#pragma unroll
        for (int l = 0; l < LDIM; ++l)
#pragma unroll
            for (int o = 0; o < OC; ++o)
                sp[o] += wp[l * OC + o] * xr[l];
    }
    float4* dst = reinterpret_cast<float4*>(s_part)
                + (((size_t)ch * NC + n) * BATCH + t) * 4;
    const float inv = 1.0f / 256.0f;
    dst[0] = make_float4(sp[0]*inv,  sp[1]*inv,  sp[2]*inv,  sp[3]*inv);
    dst[1] = make_float4(sp[4]*inv,  sp[5]*inv,  sp[6]*inv,  sp[7]*inv);
    dst[2] = make_float4(sp[8]*inv,  sp[9]*inv,  sp[10]*inv, sp[11]*inv);
    dst[3] = make_float4(sp[12]*inv, sp[13]*inv, sp[14]*inv, sp[15]*inv);
}

// ---------------------------------------------------------------------------
// KR: s[idx] = sum_ch s_part[ch][idx]; per-block n2 partial (fixed order)
// ---------------------------------------------------------------------------
__global__ __launch_bounds__(256) void kR(const float* __restrict__ s_part,
                                          float* __restrict__ s,
                                          float* __restrict__ n2_part)
{
    int idx = blockIdx.x * 256 + threadIdx.x;    // 160 blocks exactly
    float acc = 0.f;
    for (int c2 = 0; c2 < NCH; ++c2) acc += s_part[(size_t)c2 * NTOT + idx];
    s[idx] = acc;
    float q = acc * acc;
#pragma unroll
    for (int m = 32; m >= 1; m >>= 1) q += __shfl_xor(q, m, 64);
    __shared__ float r[4];
    int lane = threadIdx.x & 63, wid = threadIdx.x >> 6;
    if (lane == 0) r[wid] = q;
    __syncthreads();
    if (threadIdx.x == 0) n2_part[blockIdx.x] = r[0] + r[1] + r[2] + r[3];
}

// ---------------------------------------------------------------------------
// KB: one fused routing step. Per i: p = priors(:,i), beta = p.v (+old),
//     in-block softmax over b (block owns all 256 b) -> c, s_part += c*p.
//     p stays live in registers: ONE priors recompute instead of two.
//     FIRST: beta = dot, store betaT. !FIRST (last iter): beta = betaT+dot,
//     no store.
// ---------------------------------------------------------------------------
template<bool FIRST>
__global__ __launch_bounds__(256) void kB(
    const float* __restrict__ xT, const float* __restrict__ w,
    const float* __restrict__ s, const float* __restrict__ n2_part,
    float* __restrict__ betaT, float* __restrict__ s_part)
{
    __shared__ float redA[2][4];
    __shared__ float redW[4];
    int t = threadIdx.x, lane = t & 63, wid = t >> 6;
    int wg = xcd_swizzle(blockIdx.x, NBLK);
    int n  = wg / NCH, ch = wg % NCH;
    int i0 = ch * CH;

    // squash scale from n2 partials (redundant per block, fixed order)
    float q = (t < NRED) ? n2_part[t] : 0.f;
#pragma unroll
    for (int m = 32; m >= 1; m >>= 1) q += __shfl_xor(q, m, 64);
    if (lane == 0) redW[wid] = q;
    __syncthreads();
    float n2 = redW[0] + redW[1] + redW[2] + redW[3];
    float sc = sqrtf(n2) / (1.0f + n2);

    // v[n,b,:] = s * scale
    float v[OC];
    {
        const float4* svp = reinterpret_cast<const float4*>(s)
                          + ((size_t)n * BATCH + t) * 4;
        float4 a = svp[0], b4 = svp[1], c4 = svp[2], d4 = svp[3];
        v[0]=a.x*sc;  v[1]=a.y*sc;  v[2]=a.z*sc;  v[3]=a.w*sc;
        v[4]=b4.x*sc; v[5]=b4.y*sc; v[6]=b4.z*sc; v[7]=b4.w*sc;
        v[8]=c4.x*sc; v[9]=c4.y*sc; v[10]=c4.z*sc;v[11]=c4.w*sc;
        v[12]=d4.x*sc;v[13]=d4.y*sc;v[14]=d4.z*sc;v[15]=d4.w*sc;
    }

    float sp[OC];
#pragma unroll
    for (int o = 0; o < OC; ++o) sp[o] = 0.f;

    for (int ii = 0; ii < CH; ++ii) {
        int i = i0 + ii;
        const float4* xp = reinterpret_cast<const float4*>(xT)
                         + ((size_t)i * BATCH + t) * 2;
        float4 xa = xp[0], xb = xp[1];
        float xr[8] = {xa.x, xa.y, xa.z, xa.w, xb.x, xb.y, xb.z, xb.w};
        const float* wp = w + (size_t)__builtin_amdgcn_readfirstlane(
                                  (n * IC + i) * (LDIM * OC));
        float p[OC];
#pragma unroll
        for (int o = 0; o < OC; ++o) p[o] = 0.f;
#pragma unroll
        for (int l = 0; l < LDIM; ++l)
#pragma unroll
            for (int o = 0; o < OC; ++o)
                p[o] += wp[l * OC + o] * xr[l];

        float dot = 0.f;
#pragma unroll
        for (int o = 0; o < OC; ++o) dot += p[o] * v[o];

        size_t bidx = ((size_t)n * IC + i) * BATCH + t;   // coalesced
        float beta;
        if (FIRST) { beta = dot; betaT[bidx] = beta; }
        else       { beta = betaT[bidx] + dot; }

        // in-block softmax over b: exp-sum across 4 waves (dbl-buffered LDS)
        float e = __expf(beta);
        float es = e;
#pragma unroll
        for (int m = 1; m < 64; m <<= 1) es += __shfl_xor(es, m, 64);
        if (lane == 0) redA[ii & 1][wid] = es;
        __syncthreads();
        float denom = redA[ii & 1][0] + redA[ii & 1][1]
                    + redA[ii & 1][2] + redA[ii & 1][3];
        float c = e * (1.0f / denom);
#pragma unroll
        for (int o = 0; o < OC; ++o) sp[o] += c * p[o];
    }

    float4* dst = reinterpret_cast<float4*>(s_part)
                + (((size_t)ch * NC + n) * BATCH + t) * 4;
    dst[0] = make_float4(sp[0],  sp[1],  sp[2],  sp[3]);
    dst[1] = make_float4(sp[4],  sp[5],  sp[6],  sp[7]);
    dst[2] = make_float4(sp[8],  sp[9],  sp[10], sp[11]);
    dst[3] = make_float4(sp[12], sp[13], sp[14], sp[15]);
}

// ---------------------------------------------------------------------------
// K_OUT: scale from n2 partials; out = s * scale
// ---------------------------------------------------------------------------
__global__ __launch_bounds__(256) void k_out(const float* __restrict__ s,
                                             const float* __restrict__ n2_part,
                                             float* __restrict__ out)
{
    int t = threadIdx.x, lane = t & 63, wid = t >> 6;
    float q = (t < NRED) ? n2_part[t] : 0.f;
#pragma unroll
    for (int m = 32; m >= 1; m >>= 1) q += __shfl_xor(q, m, 64);
    __shared__ float r[4];
    if (lane == 0) r[wid] = q;
    __syncthreads();
    float n2 = r[0] + r[1] + r[2] + r[3];
    float sc = sqrtf(n2) / (1.0f + n2);
    int idx = blockIdx.x * 256 + t;
    out[idx] = s[idx] * sc;
}

// ---------------------------------------------------------------------------
extern "C" void kernel_launch(void* const* d_in, const int* in_sizes, int n_in,
                              void* d_out, int out_size, void* d_ws, size_t ws_size,
                              hipStream_t stream)
{
    const float* x = (const float*)d_in[0];   // [256,1152,8]
    const float* w = (const float*)d_in[1];   // [10,1152,8,16]
    float* out = (float*)d_out;               // 40960 floats
    float* ws  = (float*)d_ws;

    float* xT      = ws;                                        // 2,359,296
    float* betaT   = xT + (size_t)IC * BATCH * LDIM;            // 2,949,120
    float* s       = betaT + (size_t)NC * IC * BATCH;           //    40,960
    float* s_part  = s + (size_t)NC * BATCH * OC;               // 3,932,160
    float* n2_part = s_part + (size_t)NCH * NC * BATCH * OC;    //       160
    // total ~37 MB of workspace

    dim3 blk(256);

    k0_xT<<<2304, blk, 0, stream>>>(x, xT);
    // iter 1: c uniform
    kA<<<NBLK, blk, 0, stream>>>(xT, w, s_part);
    kR<<<NRED, blk, 0, stream>>>(s_part, s, n2_part);
    // iter 2 fused: beta1 = p.v0, softmax, s1
    kB<true><<<NBLK, blk, 0, stream>>>(xT, w, s, n2_part, betaT, s_part);
    kR<<<NRED, blk, 0, stream>>>(s_part, s, n2_part);
    // iter 3 fused: beta2 = beta1 + p.v1, softmax, s2
    kB<false><<<NBLK, blk, 0, stream>>>(xT, w, s, n2_part, betaT, s_part);
    kR<<<NRED, blk, 0, stream>>>(s_part, s, n2_part);
    // final squash -> out
    k_out<<<NRED, blk, 0, stream>>>(s, n2_part, out);
}